// Round 7
// baseline (163.267 us; speedup 1.0000x reference)
//
#include <hip/hip_runtime.h>

#define DH 128
#define DW 128
#define DB 8
#define DC 64
constexpr int HW = DH * DW;

typedef __attribute__((ext_vector_type(4))) float f32x4;
typedef __attribute__((ext_vector_type(16))) float f32x16;
typedef __attribute__((ext_vector_type(8))) short bf16x8;
typedef __attribute__((ext_vector_type(4))) unsigned int u32x4;

__device__ __forceinline__ unsigned short f2b(float f) {
    unsigned int u = __builtin_bit_cast(unsigned int, f);
    u = (u + 0x7FFFu + ((u >> 16) & 1u)) >> 16;   // RNE
    return (unsigned short)u;
}
__device__ __forceinline__ float b2f(unsigned short h) {
    unsigned int u = ((unsigned int)h) << 16;
    return __builtin_bit_cast(float, u);
}

// ---------- prep: NCHW fp32 -> HWC bf16 transpose + weight repack ----------
// blocks [0,2048): xpose; blocks [2048,2480): weights OIHW fp32 -> [tap][co][ci] bf16
__global__ __launch_bounds__(256) void prep_kernel(
    const float* __restrict__ x, const float* __restrict__ wo,
    const float* __restrict__ wc, unsigned short* __restrict__ xh,
    unsigned short* __restrict__ wt1, unsigned short* __restrict__ wt2)
{
    __shared__ unsigned short smx[64 * 80];
    const int blk = blockIdx.x;
    const int t = threadIdx.x;
    if (blk < 2048) {
        const int b = blk >> 8;
        const int p0 = (blk & 255) * 64;
        const int ci = t >> 2, q = t & 3;
        const float* xr = x + ((size_t)b * 64 + ci) * HW + p0;
#pragma unroll
        for (int j = 0; j < 4; ++j) {
            int pix = (j * 4 + q) * 4;
            float4 v = *(const float4*)(xr + pix);
            smx[(pix + 0) * 80 + ci] = f2b(v.x);
            smx[(pix + 1) * 80 + ci] = f2b(v.y);
            smx[(pix + 2) * 80 + ci] = f2b(v.z);
            smx[(pix + 3) * 80 + ci] = f2b(v.w);
        }
        __syncthreads();
        unsigned short* outp = xh + ((size_t)b * HW + p0) * 64;
        for (int i = t; i < 512; i += 256) {
            int pix = i >> 3, cq = i & 7;
            u32x4 v = *(const u32x4*)(smx + pix * 80 + cq * 8);
            *(u32x4*)(outp + pix * 64 + cq * 8) = v;
        }
    } else {
        int id = (blk - 2048) * 256 + t;
        const int N1 = 9 * 128 * 64, N2 = 9 * 64 * 64;
        if (id < N1) {
            int tp = id / (128 * 64);
            int rem = id - tp * 128 * 64;
            int co = rem >> 6, ci = rem & 63;
            wt1[id] = f2b(wo[(co * 64 + ci) * 9 + tp]);
        } else if (id < N1 + N2) {
            int k = id - N1;
            int tp = k / (64 * 64);
            int rem = k - tp * 64 * 64;
            int co = rem >> 6, ci = rem & 63;
            wt2[k] = f2b(wc[(co * 64 + ci) * 9 + tp]);
        }
    }
}

// ---------- conv1 3x3 implicit GEMM, 32x32x16 bf16 MFMA ----------
// (unchanged from passing round-6 version)
template<int COUT, int MI, bool HWC_BF16_OUT>
__global__ __launch_bounds__(512, 4) void conv_mfma_kernel(
    const unsigned short* __restrict__ xh,   // bf16 HWC [b][p][64]
    const unsigned short* __restrict__ wt,   // bf16 [9][COUT][64]
    const float* __restrict__ bias,
    void* __restrict__ outp)
{
    constexpr int WBYTES = COUT * 64 * 2;
    constexpr int SPASS = WBYTES / 8192;
    __shared__ char sm[41472 + 2 * WBYTES];
    char* const wbuf0 = sm + 41472;
    char* const wbuf1 = sm + 41472 + WBYTES;

    const int tid = threadIdx.x;
    const int b = blockIdx.y;
    const int ty0 = (blockIdx.x >> 3) << 4;
    const int tx0 = (blockIdx.x & 7) << 4;
    const unsigned short* xb = xh + (size_t)b * HW * 64;

    u32x4 wreg[SPASS];
    {
        const char* wsrc = (const char*)wt;
#pragma unroll
        for (int s = 0; s < SPASS; ++s) {
            int L = (s * 512 + tid) * 16;
            wreg[s] = *(const u32x4*)(wsrc + (L ^ (((L >> 7) & 7) << 4)));
        }
    }
    for (int i = tid; i < 2592; i += 512) {
        int hp = i >> 3, cq = i & 7;
        int hy = hp / 18, hx = hp - hy * 18;
        int gy = ty0 + hy - 1, gx = tx0 + hx - 1;
        u32x4 v = {0u, 0u, 0u, 0u};
        if ((unsigned)gy < 128u && (unsigned)gx < 128u)
            v = *(const u32x4*)(xb + (size_t)((gy << 7) + gx) * 64 + cq * 8);
        *(u32x4*)(sm + ((hp * 128 + cq * 16) ^ ((hp & 7) << 4))) = v;
    }
#pragma unroll
    for (int s = 0; s < SPASS; ++s) {
        int L = (s * 512 + tid) * 16;
        *(u32x4*)(wbuf0 + L) = wreg[s];
    }
    __syncthreads();

    const int lane = tid & 63;
    const int wv = tid >> 6;
    const int wm = wv & 1;
    const int wn = wv >> 1;
    const int n = lane & 31;
    const int half = lane >> 5;
    const int px = n & 15;
    const int pyb = wn * 4 + (n >> 4);
    const int swzA = (lane & 7) << 4;
    const int rowA = (wm * (MI * 32) + n) * 128 + half * 16;

    int hp0[2];
#pragma unroll
    for (int ni = 0; ni < 2; ++ni)
        hp0[ni] = (pyb + ni * 2) * 18 + px;

    f32x16 acc[MI][2];
#pragma unroll
    for (int mi = 0; mi < MI; ++mi)
#pragma unroll
        for (int ni = 0; ni < 2; ++ni)
#pragma unroll
            for (int e = 0; e < 16; ++e) acc[mi][ni][e] = 0.f;

#pragma unroll
    for (int t9 = 0; t9 < 9; ++t9) {
        const int toff = (t9 / 3) * 18 + (t9 % 3);
        const char* wb = (t9 & 1) ? wbuf1 : wbuf0;
        u32x4 wr[SPASS];
        if (t9 < 8) {
            const char* wsrc = (const char*)(wt + (size_t)(t9 + 1) * COUT * 64);
#pragma unroll
            for (int s = 0; s < SPASS; ++s) {
                int L = (s * 512 + tid) * 16;
                wr[s] = *(const u32x4*)(wsrc + (L ^ (((L >> 7) & 7) << 4)));
            }
        }
#pragma unroll
        for (int kk = 0; kk < 4; ++kk) {
            const int kcol = kk * 32;
            bf16x8 a[MI], bv[2];
#pragma unroll
            for (int mi = 0; mi < MI; ++mi)
                a[mi] = *(const bf16x8*)(wb + ((rowA + mi * 4096 + kcol) ^ swzA));
#pragma unroll
            for (int ni = 0; ni < 2; ++ni) {
                int hp = hp0[ni] + toff;
                bv[ni] = *(const bf16x8*)(sm + ((hp * 128 + kcol + half * 16) ^ ((hp & 7) << 4)));
            }
#pragma unroll
            for (int mi = 0; mi < MI; ++mi)
#pragma unroll
                for (int ni = 0; ni < 2; ++ni)
                    acc[mi][ni] = __builtin_amdgcn_mfma_f32_32x32x16_bf16(
                        a[mi], bv[ni], acc[mi][ni], 0, 0, 0);
        }
        if (t9 < 8) {
            char* wbn = ((t9 + 1) & 1) ? wbuf1 : wbuf0;
#pragma unroll
            for (int s = 0; s < SPASS; ++s) {
                int L = (s * 512 + tid) * 16;
                *(u32x4*)(wbn + L) = wr[s];
            }
        }
        __syncthreads();
    }

#pragma unroll
    for (int ni = 0; ni < 2; ++ni) {
        int py = pyb + ni * 2;
        int gp = (ty0 + py) * 128 + tx0 + px;
        if (HWC_BF16_OUT) {
            unsigned short* o = (unsigned short*)outp + ((size_t)b * HW + gp) * COUT;
#pragma unroll
            for (int mi = 0; mi < MI; ++mi) {
                int cob = wm * (MI * 32) + mi * 32 + half * 4;
#pragma unroll
                for (int g = 0; g < 4; ++g) {
                    uint2 pk;
                    pk.x = (unsigned)f2b(acc[mi][ni][g * 4 + 0]) |
                           ((unsigned)f2b(acc[mi][ni][g * 4 + 1]) << 16);
                    pk.y = (unsigned)f2b(acc[mi][ni][g * 4 + 2]) |
                           ((unsigned)f2b(acc[mi][ni][g * 4 + 3]) << 16);
                    *(uint2*)(o + cob + g * 8) = pk;
                }
            }
        } else {
            float* o = (float*)outp + (size_t)b * COUT * HW + gp;
#pragma unroll
            for (int mi = 0; mi < MI; ++mi) {
                int cob = wm * (MI * 32) + mi * 32 + half * 4;
#pragma unroll
                for (int g = 0; g < 4; ++g)
#pragma unroll
                    for (int r = 0; r < 4; ++r) {
                        int co = cob + g * 8 + r;
                        o[(size_t)co * HW] = acc[mi][ni][g * 4 + r] + bias[co];
                    }
            }
        }
    }
}

// ---------- fused deform + conv2 ----------
// Per block: compute the deformed bilinear values for this tile's 18x18x64
// halo directly into swizzled LDS, then run the conv2 MFMA loop (COUT=64,
// MI=1, fp32 NCHW out + bias). Eliminates the xdef round-trip.
__global__ __launch_bounds__(512, 4) void conv2_deform_kernel(
    const unsigned short* __restrict__ xh,    // bf16 HWC [b][p][64]
    const unsigned short* __restrict__ offs,  // bf16 HWC [b][p][128]
    const unsigned short* __restrict__ wt,    // bf16 [9][64][64]
    const float* __restrict__ bias,
    float* __restrict__ out)
{
    __shared__ char sm[41472 + 2 * 8192];
    char* const wbuf0 = sm + 41472;
    char* const wbuf1 = sm + 41472 + 8192;

    const int tid = threadIdx.x;
    const int b = blockIdx.y;
    const int ty0 = (blockIdx.x >> 3) << 4;
    const int tx0 = (blockIdx.x & 7) << 4;
    const unsigned short* xb = xh + (size_t)b * HW * 64;
    const unsigned short* ob = offs + (size_t)b * HW * 128;

    // issue weights tap0 early (pre-swizzled source, linear LDS write later)
    u32x4 wreg;
    {
        int L = tid * 16;
        wreg = *(const u32x4*)((const char*)wt + (L ^ (((L >> 7) & 7) << 4)));
    }

    // deform the halo: 324 pixels x 64 ci
    for (int i = tid; i < 324 * 64; i += 512) {
        int hp = i >> 6, ci = i & 63;
        int hy = hp / 18, hx = hp - hy * 18;
        int gy = ty0 + hy - 1, gx = tx0 + hx - 1;
        unsigned short val = 0;
        if ((unsigned)gy < 128u && (unsigned)gx < 128u) {
            int q = (gy << 7) + gx;
            int ch = 2 * ci + (q >> 13);
            int pp = (2 * q) & (HW - 1);
            float oy = b2f(ob[(size_t)pp * 128 + ch]);
            float ox = b2f(ob[(size_t)(pp + 1) * 128 + ch]);
            float cy = fminf(fmaxf(oy + (float)gy, 0.f), 127.f);
            float cx = fminf(fmaxf(ox + (float)gx, 0.f), 127.f);
            float y0f = floorf(cy), x0f = floorf(cx);
            int y0 = (int)y0f, x0i = (int)x0f;
            int y1 = (int)ceilf(cy), x1 = (int)ceilf(cx);
            const unsigned short* pl = xb + ci;
            float v_lt = b2f(pl[(size_t)(y0 * 128 + x0i) * 64]);
            float v_rb = b2f(pl[(size_t)(y1 * 128 + x1) * 64]);
            float v_lb = b2f(pl[(size_t)(y0 * 128 + x1) * 64]);
            float v_rt = b2f(pl[(size_t)(y1 * 128 + x0i) * 64]);
            float dy = cy - y0f, dxf = cx - x0f;
            float v_t = fmaf(dy, v_rt - v_lt, v_lt);
            float v_b = fmaf(dy, v_rb - v_lb, v_lb);
            val = f2b(fmaf(dxf, v_b - v_t, v_t));
        }
        *(unsigned short*)(sm + ((hp * 128 + ci * 2) ^ ((hp & 7) << 4))) = val;
    }
    *(u32x4*)(wbuf0 + tid * 16) = wreg;
    __syncthreads();

    // ---- MFMA loop: COUT=64, MI=1 ----
    const int lane = tid & 63;
    const int wv = tid >> 6;
    const int wm = wv & 1;
    const int wn = wv >> 1;
    const int n = lane & 31;
    const int half = lane >> 5;
    const int px = n & 15;
    const int pyb = wn * 4 + (n >> 4);
    const int swzA = (lane & 7) << 4;
    const int rowA = (wm * 32 + n) * 128 + half * 16;

    int hp0[2];
#pragma unroll
    for (int ni = 0; ni < 2; ++ni)
        hp0[ni] = (pyb + ni * 2) * 18 + px;

    f32x16 acc[2];
#pragma unroll
    for (int ni = 0; ni < 2; ++ni)
#pragma unroll
        for (int e = 0; e < 16; ++e) acc[ni][e] = 0.f;

#pragma unroll
    for (int t9 = 0; t9 < 9; ++t9) {
        const int toff = (t9 / 3) * 18 + (t9 % 3);
        const char* wb = (t9 & 1) ? wbuf1 : wbuf0;
        u32x4 wr;
        if (t9 < 8) {
            const char* wsrc = (const char*)(wt + (size_t)(t9 + 1) * 64 * 64);
            int L = tid * 16;
            wr = *(const u32x4*)(wsrc + (L ^ (((L >> 7) & 7) << 4)));
        }
#pragma unroll
        for (int kk = 0; kk < 4; ++kk) {
            const int kcol = kk * 32;
            bf16x8 a = *(const bf16x8*)(wb + ((rowA + kcol) ^ swzA));
            bf16x8 bv[2];
#pragma unroll
            for (int ni = 0; ni < 2; ++ni) {
                int hp = hp0[ni] + toff;
                bv[ni] = *(const bf16x8*)(sm + ((hp * 128 + kcol + half * 16) ^ ((hp & 7) << 4)));
            }
#pragma unroll
            for (int ni = 0; ni < 2; ++ni)
                acc[ni] = __builtin_amdgcn_mfma_f32_32x32x16_bf16(
                    a, bv[ni], acc[ni], 0, 0, 0);
        }
        if (t9 < 8) {
            char* wbn = ((t9 + 1) & 1) ? wbuf1 : wbuf0;
            *(u32x4*)(wbn + tid * 16) = wr;
        }
        __syncthreads();
    }

    // epilogue: fp32 NCHW + bias
#pragma unroll
    for (int ni = 0; ni < 2; ++ni) {
        int py = pyb + ni * 2;
        int gp = (ty0 + py) * 128 + tx0 + px;
        float* o = out + (size_t)b * 64 * HW + gp;
        int cob = wm * 32 + half * 4;
#pragma unroll
        for (int g = 0; g < 4; ++g)
#pragma unroll
            for (int r = 0; r < 4; ++r) {
                int co = cob + g * 8 + r;
                o[(size_t)co * HW] = acc[ni][g * 4 + r] + bias[co];
            }
    }
}

extern "C" void kernel_launch(void* const* d_in, const int* in_sizes, int n_in,
                              void* d_out, int out_size, void* d_ws, size_t ws_size,
                              hipStream_t stream) {
    const float* x      = (const float*)d_in[0];
    const float* W_off  = (const float*)d_in[1];
    const float* W_conv = (const float*)d_in[2];
    const float* b_conv = (const float*)d_in[3];

    unsigned short* xh   = (unsigned short*)d_ws;            // 16.8 MB
    unsigned short* offs = xh + (size_t)DB * HW * 64;        // 33.6 MB
    unsigned short* wt1  = offs + (size_t)DB * HW * 128;     // 147 KB
    unsigned short* wt2  = wt1 + 9 * 128 * 64;               // 74 KB
    float* out = (float*)d_out;

    // prep: xpose (2048 blocks) + weight repack (432 blocks)
    prep_kernel<<<2048 + 432, 256, 0, stream>>>(x, W_off, W_conv, xh, wt1, wt2);

    // conv1: COUT=128, MI=2, bf16 HWC offsets out
    conv_mfma_kernel<128, 2, true><<<dim3(64, DB), 512, 0, stream>>>(
        xh, wt1, nullptr, offs);

    // fused deform + conv2
    conv2_deform_kernel<<<dim3(64, DB), 512, 0, stream>>>(
        xh, offs, wt2, b_conv, out);
}